// Round 18
// baseline (608.791 us; speedup 1.0000x reference)
//
#include <hip/hip_runtime.h>
#include <math.h>

// Model: PINNDamageLocator
// conv1: (288,4,32,2048) -> bn+relu -> pool -> (288,16,16,512), SE1
// conv2: -> bn+relu -> pool -> (288,32,8,128), SE2
// conv3: -> bn+relu -> mean -> (288,64)
// then edge_fc + GNN + attention heads -> (reg[8,3], cls[8,9], ea[8,36])
//
// R18: unroll the LDS-only inner ci loops of conv2 (2 iters, full) and conv3
// (8 iters, x2) so next-ci ds_reads hide under current-ci FMA. conv1 left
// untouched (best-measured; its unroll test R10 was confounded-negative).
// R17/R16: scalar weights only pay when folded slice fits K$ (conv1 2.3KB,
// conv2 18KB/n OK; conv3 72KB/n MISSES -> keep conv3 weights in LDS).
// R15: weight re-reads were the LDS-pipe bottleneck -> scalar path for
// conv1/conv2. R13/R14: 2-way co-split, acc <= 64 VGPR. R12: full bands.
// R3: never __launch_bounds__ min-waves clamp. R4: never unroll loops
// containing GLOBAL loads (LDS-only loops are exempt). R6: no reg ping-pong.
// Spill tripwire: WRITE_SIZE ~= ideal, VGPR <= ~120.

#define GLOAD_LDS(src, dst) \
  __builtin_amdgcn_global_load_lds( \
      (const __attribute__((address_space(1))) void*)(src), \
      (__attribute__((address_space(3))) void*)(dst), 16, 0, 0)

// ---------------- weight folding (+ sesum zero-init) ----------------
__global__ void k_fold1(const float* __restrict__ w, const float* __restrict__ bs,
                        const float* __restrict__ bv, float* __restrict__ wf1,
                        float* __restrict__ sesum1)
{
  int i = blockIdx.x * blockDim.x + threadIdx.x;
  if (i < 576) {
    int co = i / 36, r = i % 36;           // r = ci*9+kk
    float s = bs[co] * rsqrtf(bv[co] + 1e-5f);
    wf1[r * 16 + co] = w[i] * s;           // [ci*9+kk][16co]
  }
  if (i < 4608) sesum1[i] = 0.f;
}

__global__ void k_fold2(const float* __restrict__ w, const float* __restrict__ bs,
                        const float* __restrict__ bv, const float* __restrict__ s1,
                        float* __restrict__ wf2, float* __restrict__ sesum2)
{
  int n = blockIdx.x;
  const float* s1n = s1 + n * 16;
  for (int i = threadIdx.x; i < 4608; i += 256) {
    int co = i / 144, r = i % 144, ci = r / 9;   // r = ci*9+kk
    float s = bs[co] * rsqrtf(bv[co] + 1e-5f);
    wf2[(size_t)n * 4608 + r * 32 + co] = w[i] * s * s1n[ci];  // [n][ci*9+kk][32co]
  }
  if (threadIdx.x < 32) sesum2[n * 32 + threadIdx.x] = 0.f;
}

// ---------------- conv1 + bn1 + relu + maxpool + SE1-sum ----------------
// grid: ((n*2 + chunk)*4 + colq), block 256 = cog(2: 8 co each) x tl(128)
__global__ __launch_bounds__(256) void k_conv1(
    const float* __restrict__ x, const float* __restrict__ wf1,
    const float* __restrict__ cb, const float* __restrict__ bs,
    const float* __restrict__ bb, const float* __restrict__ bm,
    const float* __restrict__ bv,
    float* __restrict__ h1, float* __restrict__ sesum)
{
  int bid = blockIdx.x;
  int colq = bid & 3, chunk = (bid >> 2) & 1, n = bid >> 3;
  __shared__ float tile[4][6][520];      // [ci][rowslot][4+col]; col[3]=halo
  __shared__ float bi[16];

  const float* xn = x + (size_t)n * 4 * 32 * 2048;
  const int cbase = colq * 512;
  int tid = threadIdx.x;
  if (tid < 16) {
    int c = tid;
    float s = bs[c] * rsqrtf(bv[c] + 1e-5f);
    bi[c] = bb[c] + (cb[c] - bm[c]) * s;
  }
  int wv = tid >> 6, l = tid & 63;
  const int P0 = chunk * 8;
  {  // prologue: stage input rows 2P0-1 .. 2P0+2 for all 4 ci (32 wave-gloads)
#pragma unroll
    for (int j = 0; j < 8; j++) {
      int idx = wv * 8 + j;              // 0..31
      int ci = idx >> 3, rowidx = (idx >> 1) & 3, half = idx & 1;
      int ih = 2 * P0 - 1 + rowidx;
      int slot = ((ih % 6) + 6) % 6;
      int ihc = min(max(ih, 0), 31);
      const float* src =
          xn + ((size_t)ci * 32 + ihc) * 2048 + cbase + half * 256 + 4 * l;
      GLOAD_LDS(src, &tile[ci][slot][4 + half * 256 + 4 * l]);
    }
    if (tid < 16) {
      int ri = tid & 3, ci = tid >> 2;
      int ih2 = 2 * P0 - 1 + ri, slot2 = ((ih2 % 6) + 6) % 6;
      int ihc2 = min(max(ih2, 0), 31);
      tile[ci][slot2][3] =
          colq ? xn[((size_t)ci * 32 + ihc2) * 2048 + cbase - 1] : 0.f;
    }
  }
  __syncthreads();

  int cog = tid >> 7, tl = tid & 127;
  const int cobu = __builtin_amdgcn_readfirstlane(cog * 8);  // uniform co base
  float sloc[8] = {0.f, 0.f, 0.f, 0.f, 0.f, 0.f, 0.f, 0.f};

#pragma unroll 1
  for (int pl = 0; pl < 8; pl++) {
    int p = P0 + pl;
    if (pl < 7) {  // stage rows 2p+3, 2p+4 for all 4 ci (16 wave-gloads)
#pragma unroll
      for (int j = 0; j < 4; j++) {
        int idx = wv * 4 + j;            // 0..15
        int ci = idx >> 2, rsel = (idx >> 1) & 1, half = idx & 1;
        int ih = 2 * p + 3 + rsel;
        int slot = ih % 6;
        int ihc = min(ih, 31);
        const float* src =
            xn + ((size_t)ci * 32 + ihc) * 2048 + cbase + half * 256 + 4 * l;
        GLOAD_LDS(src, &tile[ci][slot][4 + half * 256 + 4 * l]);
      }
      if (tid < 8) {
        int rs2 = tid & 1, ci2 = tid >> 1;
        int ih2 = 2 * p + 3 + rs2, slot2 = ih2 % 6, ihc2 = min(ih2, 31);
        tile[ci2][slot2][3] =
            colq ? xn[((size_t)ci2 * 32 + ihc2) * 2048 + cbase - 1] : 0.f;
      }
    }
    // compute prow p: all 4 ci from LDS, weights via scalar loads
    float acc[2][2][8];
#pragma unroll
    for (int cr = 0; cr < 2; cr++)
#pragma unroll
      for (int cc = 0; cc < 2; cc++)
#pragma unroll
        for (int k = 0; k < 8; k++) acc[cr][cc][k] = 0.f;
    const bool ok0 = (p > 0), ok3 = (p < 15);
    int slots[4];
#pragma unroll
    for (int r = 0; r < 4; r++) {
      int ih = 2 * p - 1 + r;
      slots[r] = ((ih % 6) + 6) % 6;
    }
#pragma unroll 1
    for (int ci = 0; ci < 4; ci++) {
      float strip[4][5];
#pragma unroll
      for (int r = 0; r < 4; r++) {
        bool ok = (r == 0) ? ok0 : ((r == 3) ? ok3 : true);
        if (ok) {
          float4 vA = *reinterpret_cast<const float4*>(&tile[ci][slots[r]][4 * tl]);
          float4 vB = *reinterpret_cast<const float4*>(&tile[ci][slots[r]][4 * tl + 4]);
          strip[r][0] = vA.w;
          strip[r][1] = vB.x; strip[r][2] = vB.y; strip[r][3] = vB.z; strip[r][4] = vB.w;
        } else {
          strip[r][0] = strip[r][1] = strip[r][2] = strip[r][3] = strip[r][4] = 0.f;
        }
      }
      const float* wci = wf1 + ci * 9 * 16 + cobu;
#pragma unroll
      for (int kh = 0; kh < 3; kh++) {
#pragma unroll
        for (int kw = 0; kw < 3; kw++) {
          const float4* wq = reinterpret_cast<const float4*>(wci + (kh * 3 + kw) * 16);
          float4 w0 = wq[0], w1 = wq[1];
          float wr[8] = {w0.x, w0.y, w0.z, w0.w, w1.x, w1.y, w1.z, w1.w};
#pragma unroll
          for (int cr = 0; cr < 2; cr++) {
            float v0 = strip[cr + kh][kw], v1 = strip[cr + kh][2 + kw];
#pragma unroll
            for (int k = 0; k < 8; k++) {
              acc[cr][0][k] = fmaf(v0, wr[k], acc[cr][0][k]);
              acc[cr][1][k] = fmaf(v1, wr[k], acc[cr][1][k]);
            }
          }
        }
      }
    }
    int pc = colq * 128 + tl;
#pragma unroll
    for (int k = 0; k < 8; k++) {
      float m = fmaxf(fmaxf(acc[0][0][k], acc[0][1][k]),
                      fmaxf(acc[1][0][k], acc[1][1][k]));
      float po = fmaxf(m + bi[cobu + k], 0.f);
      h1[(((size_t)n * 16 + cobu + k) * 16 + p) * 512 + pc] = po;
      sloc[k] += po;
    }
    __syncthreads();
  }
#pragma unroll
  for (int k = 0; k < 8; k++) {
    float v = sloc[k];
    for (int off = 32; off; off >>= 1) v += __shfl_down(v, off);
    if (l == 0) atomicAdd(&sesum[n * 16 + cobu + k], v);
  }
}

// ---------------- SE MLP (generic): mean -> relu fc -> sigmoid fc ----------------
__global__ void k_se(const float* __restrict__ sesum, int C, int Cr, float invcnt,
                     const float* __restrict__ w1, const float* __restrict__ b1,
                     const float* __restrict__ w2, const float* __restrict__ b2,
                     float* __restrict__ s)
{
  int n = blockIdx.x * blockDim.x + threadIdx.x;
  if (n >= 288) return;
  float y[32], t[8];
  for (int c = 0; c < C; c++) y[c] = sesum[n * C + c] * invcnt;
  for (int r = 0; r < Cr; r++) {
    float a = b1[r];
    for (int c = 0; c < C; c++) a += y[c] * w1[r * C + c];
    t[r] = fmaxf(a, 0.f);
  }
  for (int c = 0; c < C; c++) {
    float a = b2[c];
    for (int r = 0; r < Cr; r++) a += t[r] * w2[c * Cr + r];
    s[n * C + c] = 1.f / (1.f + expf(-a));
  }
}

// ---------------- conv2 (SE1 folded via wf2) + bn2 + relu + pool + SE2-sum ----------------
// grid: n*8 + ph; block 256 = cog(2: 16 co each) x tl(128)
__global__ __launch_bounds__(256) void k_conv2(
    const float* __restrict__ h1, const float* __restrict__ wf2,
    const float* __restrict__ cb, const float* __restrict__ bs,
    const float* __restrict__ bb, const float* __restrict__ bm,
    const float* __restrict__ bv,
    float* __restrict__ h2, float* __restrict__ sesum)
{
  int bid = blockIdx.x;
  int ph = bid & 7, n = bid >> 3;
  __shared__ float tile[2][2][4][520];   // [buf][ci][row][4+col], 16.6 KB
  __shared__ float bi[32];

  if (threadIdx.x < 32) {
    int c = threadIdx.x;
    float s = bs[c] * rsqrtf(bv[c] + 1e-5f);
    bi[c] = bb[c] + (cb[c] - bm[c]) * s;
  }
  if (threadIdx.x >= 64 && threadIdx.x < 128) {  // zero guard cols [0..3]
    int t2 = threadIdx.x - 64;
    int b = t2 >> 5, ci = (t2 >> 4) & 1, r = (t2 >> 2) & 3, k = t2 & 3;
    tile[b][ci][r][k] = 0.f;
  }

  const float* hn = h1 + (size_t)n * 16 * 16 * 512;
  const float* wfn = wf2 + (size_t)n * 4608;
  int wv = threadIdx.x >> 6, l = threadIdx.x & 63;

  // stage chunk c (ci = 2c, 2c+1) into buf b: 16 wave-loads, 4 per wave
  auto stage = [&](int c, int b) {
#pragma unroll
    for (int j = 0; j < 4; j++) {
      int idx = 4 * wv + j;              // 0..15
      int ci_l = idx >> 3, r = (idx >> 1) & 3, half = idx & 1;
      int ci = 2 * c + ci_l;
      int ih = min(max(2 * ph - 1 + r, 0), 15);
      const float* src = hn + ((size_t)ci * 16 + ih) * 512 + half * 256 + 4 * l;
      GLOAD_LDS(src, &tile[b][ci_l][r][4 + half * 256 + 4 * l]);
    }
  };

  stage(0, 0);
  __syncthreads();

  int cog = threadIdx.x >> 7, tl = threadIdx.x & 127;
  const int cobu = __builtin_amdgcn_readfirstlane(cog * 16);
  const bool ok0 = (ph > 0), ok3 = (ph < 7);
  float acc[2][2][16];
#pragma unroll
  for (int cr = 0; cr < 2; cr++)
#pragma unroll
    for (int cc = 0; cc < 2; cc++)
#pragma unroll
      for (int k = 0; k < 16; k++) acc[cr][cc][k] = 0.f;

#pragma unroll 1
  for (int c = 0; c < 8; c++) {
    if (c < 7) stage(c + 1, (c + 1) & 1);
    const int b = c & 1;
#pragma unroll
    for (int ci_l = 0; ci_l < 2; ci_l++) {   // LDS-only loop: fully unrolled (R18)
      int cg = 2 * c + ci_l;
      float strip[4][5];
#pragma unroll
      for (int r = 0; r < 4; r++) {
        bool ok = (r == 0) ? ok0 : ((r == 3) ? ok3 : true);
        if (ok) {
          float4 vA = *reinterpret_cast<const float4*>(&tile[b][ci_l][r][4 * tl]);
          float4 vB = *reinterpret_cast<const float4*>(&tile[b][ci_l][r][4 * tl + 4]);
          strip[r][0] = vA.w;
          strip[r][1] = vB.x; strip[r][2] = vB.y; strip[r][3] = vB.z; strip[r][4] = vB.w;
        } else {
          strip[r][0] = strip[r][1] = strip[r][2] = strip[r][3] = strip[r][4] = 0.f;
        }
      }
      const float* wci = wfn + cg * 9 * 32 + cobu;
#pragma unroll
      for (int kh = 0; kh < 3; kh++) {
#pragma unroll
        for (int kw = 0; kw < 3; kw++) {
          const float4* wq = reinterpret_cast<const float4*>(wci + (kh * 3 + kw) * 32);
          float4 w0 = wq[0], w1 = wq[1], w2 = wq[2], w3 = wq[3];
          float wr[16] = {w0.x, w0.y, w0.z, w0.w, w1.x, w1.y, w1.z, w1.w,
                          w2.x, w2.y, w2.z, w2.w, w3.x, w3.y, w3.z, w3.w};
#pragma unroll
          for (int cr = 0; cr < 2; cr++) {
            float v0 = strip[cr + kh][kw], v1 = strip[cr + kh][2 + kw];
#pragma unroll
            for (int k = 0; k < 16; k++) {
              acc[cr][0][k] = fmaf(v0, wr[k], acc[cr][0][k]);
              acc[cr][1][k] = fmaf(v1, wr[k], acc[cr][1][k]);
            }
          }
        }
      }
    }
    if (c < 7) __syncthreads();
  }

#pragma unroll
  for (int k = 0; k < 16; k++) {
    float m = fmaxf(fmaxf(acc[0][0][k], acc[0][1][k]),
                    fmaxf(acc[1][0][k], acc[1][1][k]));
    float po = fmaxf(m + bi[cobu + k], 0.f);
    h2[(((size_t)n * 32 + cobu + k) * 8 + ph) * 128 + tl] = po;
    float v = po;
    for (int off = 32; off; off >>= 1) v += __shfl_down(v, off);
    if (l == 0) atomicAdd(&sesum[n * 32 + cobu + k], v);
  }
}

// ---------------- conv3 (SE2 folded) + bn3 + relu + global mean ----------------
// grid: n*4 + cog16 (16 co each), block 256 = hh(8) x t(32)
__global__ __launch_bounds__(256) void k_conv3(
    const float* __restrict__ h2, const float* __restrict__ w,
    const float* __restrict__ cb, const float* __restrict__ bs,
    const float* __restrict__ bb, const float* __restrict__ bm,
    const float* __restrict__ bv,
    const float* __restrict__ s2, float* __restrict__ h3)
{
  int bid = blockIdx.x;
  int n = bid >> 2, cog = bid & 3;
  int hh = threadIdx.x >> 5, t = threadIdx.x & 31;
  __shared__ float tile[8][8][128];     // [ci_l][row][col], 32 KB
  __shared__ float wl[32][3][3][16];    // scales folded, 18.4 KB
  __shared__ float bi[16];
  __shared__ float red[4][16];
  const float* s2n = s2 + n * 32;
  for (int i = threadIdx.x; i < 4608; i += 256) {
    int k = i / 288, r = i % 288, ci = r / 9, kk = r % 9;
    int co = cog * 16 + k;
    float s = bs[co] * rsqrtf(bv[co] + 1e-5f);
    wl[ci][kk / 3][kk % 3][k] = w[(size_t)co * 288 + r] * s * s2n[ci];
  }
  if (threadIdx.x < 16) {
    int c = cog * 16 + threadIdx.x;
    float s = bs[c] * rsqrtf(bv[c] + 1e-5f);
    bi[threadIdx.x] = bb[c] + (cb[c] - bm[c]) * s;
  }
  const float* hn = h2 + (size_t)n * 32 * 8 * 128;
  int wv = threadIdx.x >> 6, l = threadIdx.x & 63;
  const int aoff = t ? 4 * t - 4 : 0;
  float acc[2][16];
#pragma unroll
  for (int cc = 0; cc < 2; cc++)
#pragma unroll
    for (int k = 0; k < 16; k++) acc[cc][k] = 0.f;

#pragma unroll 1
  for (int c = 0; c < 4; c++) {
    // stage 8 ci x 8 rows; one full-wave GLOAD covers 2 rows (256 floats)
    for (int i = 0; i < 8; i++) {
      int pair = wv * 8 + i;
      int ci_l = pair >> 2, r2 = (pair & 3) * 2;
      int ci = c * 8 + ci_l;
      const float* src = hn + ((size_t)ci * 8 + r2) * 128 + 4 * l;
      GLOAD_LDS(src, &tile[ci_l][r2][4 * l]);
    }
    __syncthreads();
#pragma unroll 2
    for (int ci_l = 0; ci_l < 8; ci_l++) {   // LDS-only loop: unroll 2 (R18)
      int cg = c * 8 + ci_l;
      float strip[3][5];
#pragma unroll
      for (int r = 0; r < 3; r++) {
        int ih = hh - 1 + r;
        if (ih >= 0 && ih <= 7) {
          float4 vB = *reinterpret_cast<const float4*>(&tile[ci_l][ih][4 * t]);
          float4 vA = *reinterpret_cast<const float4*>(&tile[ci_l][ih][aoff]);
          strip[r][0] = t ? vA.w : 0.f;
          strip[r][1] = vB.x; strip[r][2] = vB.y; strip[r][3] = vB.z; strip[r][4] = vB.w;
        } else {
          strip[r][0] = strip[r][1] = strip[r][2] = strip[r][3] = strip[r][4] = 0.f;
        }
      }
#pragma unroll
      for (int kh = 0; kh < 3; kh++) {
#pragma unroll
        for (int kw = 0; kw < 3; kw++) {
          const float4* wp = reinterpret_cast<const float4*>(&wl[cg][kh][kw][0]);
          float4 w0 = wp[0], w1 = wp[1], w2 = wp[2], w3 = wp[3];
          float wr[16] = {w0.x, w0.y, w0.z, w0.w, w1.x, w1.y, w1.z, w1.w,
                          w2.x, w2.y, w2.z, w2.w, w3.x, w3.y, w3.z, w3.w};
          float v0 = strip[kh][kw], v1 = strip[kh][2 + kw];
#pragma unroll
          for (int k = 0; k < 16; k++) {
            acc[0][k] = fmaf(v0, wr[k], acc[0][k]);
            acc[1][k] = fmaf(v1, wr[k], acc[1][k]);
          }
        }
      }
    }
    __syncthreads();
  }
#pragma unroll
  for (int k = 0; k < 16; k++)
    acc[0][k] = fmaxf(acc[0][k] + bi[k], 0.f) + fmaxf(acc[1][k] + bi[k], 0.f);
#pragma unroll
  for (int k = 0; k < 16; k++) {
    float v = acc[0][k];
    for (int off = 32; off; off >>= 1) v += __shfl_down(v, off);
    if (l == 0) red[wv][k] = v;
  }
  __syncthreads();
  if (threadIdx.x < 16) {
    int k = threadIdx.x;
    float tt = red[0][k] + red[1][k] + red[2][k] + red[3][k];
    h3[n * 64 + cog * 16 + k] = tt * (1.f / 512.f);
  }
}

// ---------------- head: edge_fc + GNN scatter + e2n + attention + outputs ----------------
__global__ __launch_bounds__(256) void k_head(
    const float* __restrict__ h3,
    const float* __restrict__ efw, const float* __restrict__ efb,
    const float* __restrict__ ew,
    const float* __restrict__ e2nw, const float* __restrict__ e2nb,
    const float* __restrict__ a1w, const float* __restrict__ a1b,
    const float* __restrict__ a2w,
    const float* __restrict__ clsw, const float* __restrict__ clsb,
    const float* __restrict__ regw, const float* __restrict__ regb,
    float* __restrict__ out)
{
  int b = blockIdx.x;
  int tid = threadIdx.x;
  __shared__ float ef[36][64];
  __shared__ float nin[12][64];
  __shared__ float nd[12][128];
  __shared__ float tmp[12][64];
  __shared__ float spw[36], aw[12], scv[12], g[128], ea[36];
  if (tid < 36) {
    float xw = ew[tid];
    spw[tid] = (xw > 20.f) ? xw : log1pf(expf(xw));
  }
  __syncthreads();
  for (int idx = tid; idx < 36 * 64; idx += 256) {
    int e = idx >> 6, d = idx & 63;
    const float* hr = h3 + (size_t)(b * 36 + e) * 64;
    const float* wr = efw + d * 64;
    float a = efb[d];
    for (int k = 0; k < 64; k++) a += hr[k] * wr[k];
    ef[e][d] = fmaxf(a, 0.f) * spw[e];
  }
  __syncthreads();
  for (int idx = tid; idx < 12 * 64; idx += 256) {
    int j = idx >> 6, d = idx & 63;
    float a = 0.f;
    if (j < 6) { for (int i = 0; i < 6; i++) a += ef[j * 6 + i][d]; }
    else       { for (int i = 0; i < 6; i++) a += ef[i * 6 + (j - 6)][d]; }
    nin[j][d] = a;
  }
  __syncthreads();
  for (int idx = tid; idx < 12 * 128; idx += 256) {
    int j = idx >> 7, d = idx & 127;
    const float* wr = e2nw + d * 64;
    float a = e2nb[d];
    for (int k = 0; k < 64; k++) a += nin[j][k] * wr[k];
    nd[j][d] = fmaxf(a, 0.f);
  }
  __syncthreads();
  for (int idx = tid; idx < 12 * 64; idx += 256) {
    int j = idx >> 6, hh = idx & 63;
    const float* wr = a1w + hh * 128;
    float a = a1b[hh];
    for (int k = 0; k < 128; k++) a += nd[j][k] * wr[k];
    tmp[j][hh] = tanhf(a) * a2w[hh];
  }
  __syncthreads();
  if (tid < 12) {
    float a = 0.f;
    for (int h = 0; h < 64; h++) a += tmp[tid][h];
    scv[tid] = a;
  }
  __syncthreads();
  if (tid == 0) {
    float m = scv[0];
    for (int j = 1; j < 12; j++) m = fmaxf(m, scv[j]);
    float s = 0.f;
    for (int j = 0; j < 12; j++) { float z = expf(scv[j] - m); aw[j] = z; s += z; }
    float inv = 1.f / s;
    for (int j = 0; j < 12; j++) aw[j] *= inv;
    float rs = 0.f;
    for (int e = 0; e < 36; e++) { float r = aw[e / 6] * aw[6 + e % 6]; ea[e] = r; rs += r; }
    float inv2 = 1.f / (rs + 1e-8f);
    for (int e = 0; e < 36; e++) ea[e] *= inv2;
  }
  __syncthreads();
  if (tid < 36) out[96 + b * 36 + tid] = ea[tid];
  if (tid < 128) {
    float a = 0.f;
    for (int j = 0; j < 12; j++) a += nd[j][tid] * aw[j];
    g[tid] = a;
  }
  __syncthreads();
  if (tid < 3) {
    const float* wr = regw + tid * 128;
    float a = regb[tid];
    for (int k = 0; k < 128; k++) a += g[k] * wr[k];
    out[b * 3 + tid] = a;
  }
  if (tid >= 64 && tid < 73) {
    int i = tid - 64;
    const float* wr = clsw + i * 128;
    float a = clsb[i];
    for (int k = 0; k < 128; k++) a += g[k] * wr[k];
    out[24 + b * 9 + i] = a;
  }
}

extern "C" void kernel_launch(void* const* d_in, const int* in_sizes, int n_in,
                              void* d_out, int out_size, void* d_ws, size_t ws_size,
                              hipStream_t stream) {
  const float* x      = (const float*)d_in[0];
  const float* c1w    = (const float*)d_in[1];
  const float* c1b    = (const float*)d_in[2];
  const float* bn1s   = (const float*)d_in[3];
  const float* bn1b   = (const float*)d_in[4];
  const float* bn1m   = (const float*)d_in[5];
  const float* bn1v   = (const float*)d_in[6];
  const float* se1w1  = (const float*)d_in[7];
  const float* se1b1  = (const float*)d_in[8];
  const float* se1w2  = (const float*)d_in[9];
  const float* se1b2  = (const float*)d_in[10];
  const float* c2w    = (const float*)d_in[11];
  const float* c2b    = (const float*)d_in[12];
  const float* bn2s   = (const float*)d_in[13];
  const float* bn2b   = (const float*)d_in[14];
  const float* bn2m   = (const float*)d_in[15];
  const float* bn2v   = (const float*)d_in[16];
  const float* se2w1  = (const float*)d_in[17];
  const float* se2b1  = (const float*)d_in[18];
  const float* se2w2  = (const float*)d_in[19];
  const float* se2b2  = (const float*)d_in[20];
  const float* c3w    = (const float*)d_in[21];
  const float* c3b    = (const float*)d_in[22];
  const float* bn3s   = (const float*)d_in[23];
  const float* bn3b   = (const float*)d_in[24];
  const float* bn3m   = (const float*)d_in[25];
  const float* bn3v   = (const float*)d_in[26];
  const float* efw    = (const float*)d_in[27];
  const float* efb    = (const float*)d_in[28];
  const float* ew     = (const float*)d_in[29];
  const float* e2nw   = (const float*)d_in[30];
  const float* e2nb   = (const float*)d_in[31];
  const float* a1w    = (const float*)d_in[32];
  const float* a1b    = (const float*)d_in[33];
  const float* a2w    = (const float*)d_in[34];
  const float* clsw   = (const float*)d_in[35];
  const float* clsb   = (const float*)d_in[36];
  const float* regw   = (const float*)d_in[37];
  const float* regb   = (const float*)d_in[38];

  float* ws = (float*)d_ws;
  float* h1     = ws;                        // 288*16*16*512 = 37,748,736 f
  float* h2     = h1 + 37748736;             // 288*32*8*128  =  9,437,184 f
  float* sesum1 = h2 + 9437184;              // 4608 f
  float* s1     = sesum1 + 4608;             // 4608 f
  float* sesum2 = s1 + 4608;                 // 9216 f
  float* s2     = sesum2 + 9216;             // 9216 f
  float* h3     = s2 + 9216;                 // 18432 f
  float* wf1    = h3 + 18432;                // 576 f
  float* wf2    = wf1 + 576;                 // 288*4608 = 1,327,104 f (~5.3 MB)

  k_fold1<<<18, 256, 0, stream>>>(c1w, bn1s, bn1v, wf1, sesum1);
  k_conv1<<<288 * 8, 256, 0, stream>>>(x, wf1, c1b, bn1s, bn1b, bn1m, bn1v, h1, sesum1);
  k_se<<<5, 64, 0, stream>>>(sesum1, 16, 4, 1.f / 8192.f, se1w1, se1b1, se1w2, se1b2, s1);
  k_fold2<<<288, 256, 0, stream>>>(c2w, bn2s, bn2v, s1, wf2, sesum2);
  k_conv2<<<288 * 8, 256, 0, stream>>>(h1, wf2, c2b, bn2s, bn2b, bn2m, bn2v, h2, sesum2);
  k_se<<<5, 64, 0, stream>>>(sesum2, 32, 8, 1.f / 1024.f, se2w1, se2b1, se2w2, se2b2, s2);
  k_conv3<<<288 * 4, 256, 0, stream>>>(h2, c3w, c3b, bn3s, bn3b, bn3m, bn3v, s2, h3);
  k_head<<<8, 256, 0, stream>>>(h3, efw, efb, ew, e2nw, e2nb, a1w, a1b, a2w,
                                clsw, clsb, regw, regb, (float*)d_out);
}

// Round 19
// 471.095 us; speedup vs baseline: 1.2923x; 1.2923x over previous
//
#include <hip/hip_runtime.h>
#include <math.h>

// Model: PINNDamageLocator
// conv1: (288,4,32,2048) -> bn+relu -> pool -> (288,16,16,512), SE1
// conv2: -> bn+relu -> pool -> (288,32,8,128), SE2
// conv3: -> bn+relu -> mean -> (288,64)
// then edge_fc + GNN + attention heads -> (reg[8,3], cls[8,9], ea[8,36])
//
// R19: exact revert to R17 (best measured: 472us). R18 post-mortem: fully
// unrolling conv2's LDS-only ci loop DOUBLED conv2's time (120->257us, no
// spill, VALUBusy up -> more instructions, likely demoted uniform s_loads).
// Amended rule: NO unrolling of conv inner loops, period (R4/R10/R18 all
// regressed). The compiler's unroll-1 schedule + multi-wave overlap wins.
// R16/R17: scalar weights only pay when folded slice fits K$ (conv1 2.3KB,
// conv2 18KB/n OK; conv3 72KB/n misses -> conv3 keeps LDS weights).
// R15: weight re-reads were the LDS-pipe bottleneck -> scalar for conv1/2.
// R13/R14: 2-way co-split, acc <= 64 VGPR. R12: full-width bands.
// R3: never __launch_bounds__ min-waves clamp. R6: no reg ping-pong.
// Spill tripwire: WRITE_SIZE ~= ideal, VGPR <= ~120.

#define GLOAD_LDS(src, dst) \
  __builtin_amdgcn_global_load_lds( \
      (const __attribute__((address_space(1))) void*)(src), \
      (__attribute__((address_space(3))) void*)(dst), 16, 0, 0)

// ---------------- weight folding (+ sesum zero-init) ----------------
__global__ void k_fold1(const float* __restrict__ w, const float* __restrict__ bs,
                        const float* __restrict__ bv, float* __restrict__ wf1,
                        float* __restrict__ sesum1)
{
  int i = blockIdx.x * blockDim.x + threadIdx.x;
  if (i < 576) {
    int co = i / 36, r = i % 36;           // r = ci*9+kk
    float s = bs[co] * rsqrtf(bv[co] + 1e-5f);
    wf1[r * 16 + co] = w[i] * s;           // [ci*9+kk][16co]
  }
  if (i < 4608) sesum1[i] = 0.f;
}

__global__ void k_fold2(const float* __restrict__ w, const float* __restrict__ bs,
                        const float* __restrict__ bv, const float* __restrict__ s1,
                        float* __restrict__ wf2, float* __restrict__ sesum2)
{
  int n = blockIdx.x;
  const float* s1n = s1 + n * 16;
  for (int i = threadIdx.x; i < 4608; i += 256) {
    int co = i / 144, r = i % 144, ci = r / 9;   // r = ci*9+kk
    float s = bs[co] * rsqrtf(bv[co] + 1e-5f);
    wf2[(size_t)n * 4608 + r * 32 + co] = w[i] * s * s1n[ci];  // [n][ci*9+kk][32co]
  }
  if (threadIdx.x < 32) sesum2[n * 32 + threadIdx.x] = 0.f;
}

// ---------------- conv1 + bn1 + relu + maxpool + SE1-sum ----------------
// grid: ((n*2 + chunk)*4 + colq), block 256 = cog(2: 8 co each) x tl(128)
__global__ __launch_bounds__(256) void k_conv1(
    const float* __restrict__ x, const float* __restrict__ wf1,
    const float* __restrict__ cb, const float* __restrict__ bs,
    const float* __restrict__ bb, const float* __restrict__ bm,
    const float* __restrict__ bv,
    float* __restrict__ h1, float* __restrict__ sesum)
{
  int bid = blockIdx.x;
  int colq = bid & 3, chunk = (bid >> 2) & 1, n = bid >> 3;
  __shared__ float tile[4][6][520];      // [ci][rowslot][4+col]; col[3]=halo
  __shared__ float bi[16];

  const float* xn = x + (size_t)n * 4 * 32 * 2048;
  const int cbase = colq * 512;
  int tid = threadIdx.x;
  if (tid < 16) {
    int c = tid;
    float s = bs[c] * rsqrtf(bv[c] + 1e-5f);
    bi[c] = bb[c] + (cb[c] - bm[c]) * s;
  }
  int wv = tid >> 6, l = tid & 63;
  const int P0 = chunk * 8;
  {  // prologue: stage input rows 2P0-1 .. 2P0+2 for all 4 ci (32 wave-gloads)
#pragma unroll
    for (int j = 0; j < 8; j++) {
      int idx = wv * 8 + j;              // 0..31
      int ci = idx >> 3, rowidx = (idx >> 1) & 3, half = idx & 1;
      int ih = 2 * P0 - 1 + rowidx;
      int slot = ((ih % 6) + 6) % 6;
      int ihc = min(max(ih, 0), 31);
      const float* src =
          xn + ((size_t)ci * 32 + ihc) * 2048 + cbase + half * 256 + 4 * l;
      GLOAD_LDS(src, &tile[ci][slot][4 + half * 256 + 4 * l]);
    }
    if (tid < 16) {
      int ri = tid & 3, ci = tid >> 2;
      int ih2 = 2 * P0 - 1 + ri, slot2 = ((ih2 % 6) + 6) % 6;
      int ihc2 = min(max(ih2, 0), 31);
      tile[ci][slot2][3] =
          colq ? xn[((size_t)ci * 32 + ihc2) * 2048 + cbase - 1] : 0.f;
    }
  }
  __syncthreads();

  int cog = tid >> 7, tl = tid & 127;
  const int cobu = __builtin_amdgcn_readfirstlane(cog * 8);  // uniform co base
  float sloc[8] = {0.f, 0.f, 0.f, 0.f, 0.f, 0.f, 0.f, 0.f};

#pragma unroll 1
  for (int pl = 0; pl < 8; pl++) {
    int p = P0 + pl;
    if (pl < 7) {  // stage rows 2p+3, 2p+4 for all 4 ci (16 wave-gloads)
#pragma unroll
      for (int j = 0; j < 4; j++) {
        int idx = wv * 4 + j;            // 0..15
        int ci = idx >> 2, rsel = (idx >> 1) & 1, half = idx & 1;
        int ih = 2 * p + 3 + rsel;
        int slot = ih % 6;
        int ihc = min(ih, 31);
        const float* src =
            xn + ((size_t)ci * 32 + ihc) * 2048 + cbase + half * 256 + 4 * l;
        GLOAD_LDS(src, &tile[ci][slot][4 + half * 256 + 4 * l]);
      }
      if (tid < 8) {
        int rs2 = tid & 1, ci2 = tid >> 1;
        int ih2 = 2 * p + 3 + rs2, slot2 = ih2 % 6, ihc2 = min(ih2, 31);
        tile[ci2][slot2][3] =
            colq ? xn[((size_t)ci2 * 32 + ihc2) * 2048 + cbase - 1] : 0.f;
      }
    }
    // compute prow p: all 4 ci from LDS, weights via scalar loads
    float acc[2][2][8];
#pragma unroll
    for (int cr = 0; cr < 2; cr++)
#pragma unroll
      for (int cc = 0; cc < 2; cc++)
#pragma unroll
        for (int k = 0; k < 8; k++) acc[cr][cc][k] = 0.f;
    const bool ok0 = (p > 0), ok3 = (p < 15);
    int slots[4];
#pragma unroll
    for (int r = 0; r < 4; r++) {
      int ih = 2 * p - 1 + r;
      slots[r] = ((ih % 6) + 6) % 6;
    }
#pragma unroll 1
    for (int ci = 0; ci < 4; ci++) {
      float strip[4][5];
#pragma unroll
      for (int r = 0; r < 4; r++) {
        bool ok = (r == 0) ? ok0 : ((r == 3) ? ok3 : true);
        if (ok) {
          float4 vA = *reinterpret_cast<const float4*>(&tile[ci][slots[r]][4 * tl]);
          float4 vB = *reinterpret_cast<const float4*>(&tile[ci][slots[r]][4 * tl + 4]);
          strip[r][0] = vA.w;
          strip[r][1] = vB.x; strip[r][2] = vB.y; strip[r][3] = vB.z; strip[r][4] = vB.w;
        } else {
          strip[r][0] = strip[r][1] = strip[r][2] = strip[r][3] = strip[r][4] = 0.f;
        }
      }
      const float* wci = wf1 + ci * 9 * 16 + cobu;
#pragma unroll
      for (int kh = 0; kh < 3; kh++) {
#pragma unroll
        for (int kw = 0; kw < 3; kw++) {
          const float4* wq = reinterpret_cast<const float4*>(wci + (kh * 3 + kw) * 16);
          float4 w0 = wq[0], w1 = wq[1];
          float wr[8] = {w0.x, w0.y, w0.z, w0.w, w1.x, w1.y, w1.z, w1.w};
#pragma unroll
          for (int cr = 0; cr < 2; cr++) {
            float v0 = strip[cr + kh][kw], v1 = strip[cr + kh][2 + kw];
#pragma unroll
            for (int k = 0; k < 8; k++) {
              acc[cr][0][k] = fmaf(v0, wr[k], acc[cr][0][k]);
              acc[cr][1][k] = fmaf(v1, wr[k], acc[cr][1][k]);
            }
          }
        }
      }
    }
    int pc = colq * 128 + tl;
#pragma unroll
    for (int k = 0; k < 8; k++) {
      float m = fmaxf(fmaxf(acc[0][0][k], acc[0][1][k]),
                      fmaxf(acc[1][0][k], acc[1][1][k]));
      float po = fmaxf(m + bi[cobu + k], 0.f);
      h1[(((size_t)n * 16 + cobu + k) * 16 + p) * 512 + pc] = po;
      sloc[k] += po;
    }
    __syncthreads();
  }
#pragma unroll
  for (int k = 0; k < 8; k++) {
    float v = sloc[k];
    for (int off = 32; off; off >>= 1) v += __shfl_down(v, off);
    if (l == 0) atomicAdd(&sesum[n * 16 + cobu + k], v);
  }
}

// ---------------- SE MLP (generic): mean -> relu fc -> sigmoid fc ----------------
__global__ void k_se(const float* __restrict__ sesum, int C, int Cr, float invcnt,
                     const float* __restrict__ w1, const float* __restrict__ b1,
                     const float* __restrict__ w2, const float* __restrict__ b2,
                     float* __restrict__ s)
{
  int n = blockIdx.x * blockDim.x + threadIdx.x;
  if (n >= 288) return;
  float y[32], t[8];
  for (int c = 0; c < C; c++) y[c] = sesum[n * C + c] * invcnt;
  for (int r = 0; r < Cr; r++) {
    float a = b1[r];
    for (int c = 0; c < C; c++) a += y[c] * w1[r * C + c];
    t[r] = fmaxf(a, 0.f);
  }
  for (int c = 0; c < C; c++) {
    float a = b2[c];
    for (int r = 0; r < Cr; r++) a += t[r] * w2[c * Cr + r];
    s[n * C + c] = 1.f / (1.f + expf(-a));
  }
}

// ---------------- conv2 (SE1 folded via wf2) + bn2 + relu + pool + SE2-sum ----------------
// grid: n*8 + ph; block 256 = cog(2: 16 co each) x tl(128)
__global__ __launch_bounds__(256) void k_conv2(
    const float* __restrict__ h1, const float* __restrict__ wf2,
    const float* __restrict__ cb, const float* __restrict__ bs,
    const float* __restrict__ bb, const float* __restrict__ bm,
    const float* __restrict__ bv,
    float* __restrict__ h2, float* __restrict__ sesum)
{
  int bid = blockIdx.x;
  int ph = bid & 7, n = bid >> 3;
  __shared__ float tile[2][2][4][520];   // [buf][ci][row][4+col], 16.6 KB
  __shared__ float bi[32];

  if (threadIdx.x < 32) {
    int c = threadIdx.x;
    float s = bs[c] * rsqrtf(bv[c] + 1e-5f);
    bi[c] = bb[c] + (cb[c] - bm[c]) * s;
  }
  if (threadIdx.x >= 64 && threadIdx.x < 128) {  // zero guard cols [0..3]
    int t2 = threadIdx.x - 64;
    int b = t2 >> 5, ci = (t2 >> 4) & 1, r = (t2 >> 2) & 3, k = t2 & 3;
    tile[b][ci][r][k] = 0.f;
  }

  const float* hn = h1 + (size_t)n * 16 * 16 * 512;
  const float* wfn = wf2 + (size_t)n * 4608;
  int wv = threadIdx.x >> 6, l = threadIdx.x & 63;

  // stage chunk c (ci = 2c, 2c+1) into buf b: 16 wave-loads, 4 per wave
  auto stage = [&](int c, int b) {
#pragma unroll
    for (int j = 0; j < 4; j++) {
      int idx = 4 * wv + j;              // 0..15
      int ci_l = idx >> 3, r = (idx >> 1) & 3, half = idx & 1;
      int ci = 2 * c + ci_l;
      int ih = min(max(2 * ph - 1 + r, 0), 15);
      const float* src = hn + ((size_t)ci * 16 + ih) * 512 + half * 256 + 4 * l;
      GLOAD_LDS(src, &tile[b][ci_l][r][4 + half * 256 + 4 * l]);
    }
  };

  stage(0, 0);
  __syncthreads();

  int cog = threadIdx.x >> 7, tl = threadIdx.x & 127;
  const int cobu = __builtin_amdgcn_readfirstlane(cog * 16);
  const bool ok0 = (ph > 0), ok3 = (ph < 7);
  float acc[2][2][16];
#pragma unroll
  for (int cr = 0; cr < 2; cr++)
#pragma unroll
    for (int cc = 0; cc < 2; cc++)
#pragma unroll
      for (int k = 0; k < 16; k++) acc[cr][cc][k] = 0.f;

#pragma unroll 1
  for (int c = 0; c < 8; c++) {
    if (c < 7) stage(c + 1, (c + 1) & 1);
    const int b = c & 1;
#pragma unroll 1
    for (int ci_l = 0; ci_l < 2; ci_l++) {
      int cg = 2 * c + ci_l;
      float strip[4][5];
#pragma unroll
      for (int r = 0; r < 4; r++) {
        bool ok = (r == 0) ? ok0 : ((r == 3) ? ok3 : true);
        if (ok) {
          float4 vA = *reinterpret_cast<const float4*>(&tile[b][ci_l][r][4 * tl]);
          float4 vB = *reinterpret_cast<const float4*>(&tile[b][ci_l][r][4 * tl + 4]);
          strip[r][0] = vA.w;
          strip[r][1] = vB.x; strip[r][2] = vB.y; strip[r][3] = vB.z; strip[r][4] = vB.w;
        } else {
          strip[r][0] = strip[r][1] = strip[r][2] = strip[r][3] = strip[r][4] = 0.f;
        }
      }
      const float* wci = wfn + cg * 9 * 32 + cobu;
#pragma unroll
      for (int kh = 0; kh < 3; kh++) {
#pragma unroll
        for (int kw = 0; kw < 3; kw++) {
          const float4* wq = reinterpret_cast<const float4*>(wci + (kh * 3 + kw) * 32);
          float4 w0 = wq[0], w1 = wq[1], w2 = wq[2], w3 = wq[3];
          float wr[16] = {w0.x, w0.y, w0.z, w0.w, w1.x, w1.y, w1.z, w1.w,
                          w2.x, w2.y, w2.z, w2.w, w3.x, w3.y, w3.z, w3.w};
#pragma unroll
          for (int cr = 0; cr < 2; cr++) {
            float v0 = strip[cr + kh][kw], v1 = strip[cr + kh][2 + kw];
#pragma unroll
            for (int k = 0; k < 16; k++) {
              acc[cr][0][k] = fmaf(v0, wr[k], acc[cr][0][k]);
              acc[cr][1][k] = fmaf(v1, wr[k], acc[cr][1][k]);
            }
          }
        }
      }
    }
    if (c < 7) __syncthreads();
  }

#pragma unroll
  for (int k = 0; k < 16; k++) {
    float m = fmaxf(fmaxf(acc[0][0][k], acc[0][1][k]),
                    fmaxf(acc[1][0][k], acc[1][1][k]));
    float po = fmaxf(m + bi[cobu + k], 0.f);
    h2[(((size_t)n * 32 + cobu + k) * 8 + ph) * 128 + tl] = po;
    float v = po;
    for (int off = 32; off; off >>= 1) v += __shfl_down(v, off);
    if (l == 0) atomicAdd(&sesum[n * 32 + cobu + k], v);
  }
}

// ---------------- conv3 (SE2 folded) + bn3 + relu + global mean ----------------
// grid: n*4 + cog16 (16 co each), block 256 = hh(8) x t(32)
__global__ __launch_bounds__(256) void k_conv3(
    const float* __restrict__ h2, const float* __restrict__ w,
    const float* __restrict__ cb, const float* __restrict__ bs,
    const float* __restrict__ bb, const float* __restrict__ bm,
    const float* __restrict__ bv,
    const float* __restrict__ s2, float* __restrict__ h3)
{
  int bid = blockIdx.x;
  int n = bid >> 2, cog = bid & 3;
  int hh = threadIdx.x >> 5, t = threadIdx.x & 31;
  __shared__ float tile[8][8][128];     // [ci_l][row][col], 32 KB
  __shared__ float wl[32][3][3][16];    // scales folded, 18.4 KB
  __shared__ float bi[16];
  __shared__ float red[4][16];
  const float* s2n = s2 + n * 32;
  for (int i = threadIdx.x; i < 4608; i += 256) {
    int k = i / 288, r = i % 288, ci = r / 9, kk = r % 9;
    int co = cog * 16 + k;
    float s = bs[co] * rsqrtf(bv[co] + 1e-5f);
    wl[ci][kk / 3][kk % 3][k] = w[(size_t)co * 288 + r] * s * s2n[ci];
  }
  if (threadIdx.x < 16) {
    int c = cog * 16 + threadIdx.x;
    float s = bs[c] * rsqrtf(bv[c] + 1e-5f);
    bi[threadIdx.x] = bb[c] + (cb[c] - bm[c]) * s;
  }
  const float* hn = h2 + (size_t)n * 32 * 8 * 128;
  int wv = threadIdx.x >> 6, l = threadIdx.x & 63;
  const int aoff = t ? 4 * t - 4 : 0;
  float acc[2][16];
#pragma unroll
  for (int cc = 0; cc < 2; cc++)
#pragma unroll
    for (int k = 0; k < 16; k++) acc[cc][k] = 0.f;

#pragma unroll 1
  for (int c = 0; c < 4; c++) {
    // stage 8 ci x 8 rows; one full-wave GLOAD covers 2 rows (256 floats)
    for (int i = 0; i < 8; i++) {
      int pair = wv * 8 + i;
      int ci_l = pair >> 2, r2 = (pair & 3) * 2;
      int ci = c * 8 + ci_l;
      const float* src = hn + ((size_t)ci * 8 + r2) * 128 + 4 * l;
      GLOAD_LDS(src, &tile[ci_l][r2][4 * l]);
    }
    __syncthreads();
#pragma unroll 1
    for (int ci_l = 0; ci_l < 8; ci_l++) {
      int cg = c * 8 + ci_l;
      float strip[3][5];
#pragma unroll
      for (int r = 0; r < 3; r++) {
        int ih = hh - 1 + r;
        if (ih >= 0 && ih <= 7) {
          float4 vB = *reinterpret_cast<const float4*>(&tile[ci_l][ih][4 * t]);
          float4 vA = *reinterpret_cast<const float4*>(&tile[ci_l][ih][aoff]);
          strip[r][0] = t ? vA.w : 0.f;
          strip[r][1] = vB.x; strip[r][2] = vB.y; strip[r][3] = vB.z; strip[r][4] = vB.w;
        } else {
          strip[r][0] = strip[r][1] = strip[r][2] = strip[r][3] = strip[r][4] = 0.f;
        }
      }
#pragma unroll
      for (int kh = 0; kh < 3; kh++) {
#pragma unroll
        for (int kw = 0; kw < 3; kw++) {
          const float4* wp = reinterpret_cast<const float4*>(&wl[cg][kh][kw][0]);
          float4 w0 = wp[0], w1 = wp[1], w2 = wp[2], w3 = wp[3];
          float wr[16] = {w0.x, w0.y, w0.z, w0.w, w1.x, w1.y, w1.z, w1.w,
                          w2.x, w2.y, w2.z, w2.w, w3.x, w3.y, w3.z, w3.w};
          float v0 = strip[kh][kw], v1 = strip[kh][2 + kw];
#pragma unroll
          for (int k = 0; k < 16; k++) {
            acc[0][k] = fmaf(v0, wr[k], acc[0][k]);
            acc[1][k] = fmaf(v1, wr[k], acc[1][k]);
          }
        }
      }
    }
    __syncthreads();
  }
#pragma unroll
  for (int k = 0; k < 16; k++)
    acc[0][k] = fmaxf(acc[0][k] + bi[k], 0.f) + fmaxf(acc[1][k] + bi[k], 0.f);
#pragma unroll
  for (int k = 0; k < 16; k++) {
    float v = acc[0][k];
    for (int off = 32; off; off >>= 1) v += __shfl_down(v, off);
    if (l == 0) red[wv][k] = v;
  }
  __syncthreads();
  if (threadIdx.x < 16) {
    int k = threadIdx.x;
    float tt = red[0][k] + red[1][k] + red[2][k] + red[3][k];
    h3[n * 64 + cog * 16 + k] = tt * (1.f / 512.f);
  }
}

// ---------------- head: edge_fc + GNN scatter + e2n + attention + outputs ----------------
__global__ __launch_bounds__(256) void k_head(
    const float* __restrict__ h3,
    const float* __restrict__ efw, const float* __restrict__ efb,
    const float* __restrict__ ew,
    const float* __restrict__ e2nw, const float* __restrict__ e2nb,
    const float* __restrict__ a1w, const float* __restrict__ a1b,
    const float* __restrict__ a2w,
    const float* __restrict__ clsw, const float* __restrict__ clsb,
    const float* __restrict__ regw, const float* __restrict__ regb,
    float* __restrict__ out)
{
  int b = blockIdx.x;
  int tid = threadIdx.x;
  __shared__ float ef[36][64];
  __shared__ float nin[12][64];
  __shared__ float nd[12][128];
  __shared__ float tmp[12][64];
  __shared__ float spw[36], aw[12], scv[12], g[128], ea[36];
  if (tid < 36) {
    float xw = ew[tid];
    spw[tid] = (xw > 20.f) ? xw : log1pf(expf(xw));
  }
  __syncthreads();
  for (int idx = tid; idx < 36 * 64; idx += 256) {
    int e = idx >> 6, d = idx & 63;
    const float* hr = h3 + (size_t)(b * 36 + e) * 64;
    const float* wr = efw + d * 64;
    float a = efb[d];
    for (int k = 0; k < 64; k++) a += hr[k] * wr[k];
    ef[e][d] = fmaxf(a, 0.f) * spw[e];
  }
  __syncthreads();
  for (int idx = tid; idx < 12 * 64; idx += 256) {
    int j = idx >> 6, d = idx & 63;
    float a = 0.f;
    if (j < 6) { for (int i = 0; i < 6; i++) a += ef[j * 6 + i][d]; }
    else       { for (int i = 0; i < 6; i++) a += ef[i * 6 + (j - 6)][d]; }
    nin[j][d] = a;
  }
  __syncthreads();
  for (int idx = tid; idx < 12 * 128; idx += 256) {
    int j = idx >> 7, d = idx & 127;
    const float* wr = e2nw + d * 64;
    float a = e2nb[d];
    for (int k = 0; k < 64; k++) a += nin[j][k] * wr[k];
    nd[j][d] = fmaxf(a, 0.f);
  }
  __syncthreads();
  for (int idx = tid; idx < 12 * 64; idx += 256) {
    int j = idx >> 6, hh = idx & 63;
    const float* wr = a1w + hh * 128;
    float a = a1b[hh];
    for (int k = 0; k < 128; k++) a += nd[j][k] * wr[k];
    tmp[j][hh] = tanhf(a) * a2w[hh];
  }
  __syncthreads();
  if (tid < 12) {
    float a = 0.f;
    for (int h = 0; h < 64; h++) a += tmp[tid][h];
    scv[tid] = a;
  }
  __syncthreads();
  if (tid == 0) {
    float m = scv[0];
    for (int j = 1; j < 12; j++) m = fmaxf(m, scv[j]);
    float s = 0.f;
    for (int j = 0; j < 12; j++) { float z = expf(scv[j] - m); aw[j] = z; s += z; }
    float inv = 1.f / s;
    for (int j = 0; j < 12; j++) aw[j] *= inv;
    float rs = 0.f;
    for (int e = 0; e < 36; e++) { float r = aw[e / 6] * aw[6 + e % 6]; ea[e] = r; rs += r; }
    float inv2 = 1.f / (rs + 1e-8f);
    for (int e = 0; e < 36; e++) ea[e] *= inv2;
  }
  __syncthreads();
  if (tid < 36) out[96 + b * 36 + tid] = ea[tid];
  if (tid < 128) {
    float a = 0.f;
    for (int j = 0; j < 12; j++) a += nd[j][tid] * aw[j];
    g[tid] = a;
  }
  __syncthreads();
  if (tid < 3) {
    const float* wr = regw + tid * 128;
    float a = regb[tid];
    for (int k = 0; k < 128; k++) a += g[k] * wr[k];
    out[b * 3 + tid] = a;
  }
  if (tid >= 64 && tid < 73) {
    int i = tid - 64;
    const float* wr = clsw + i * 128;
    float a = clsb[i];
    for (int k = 0; k < 128; k++) a += g[k] * wr[k];
    out[24 + b * 9 + i] = a;
  }
}

extern "C" void kernel_launch(void* const* d_in, const int* in_sizes, int n_in,
                              void* d_out, int out_size, void* d_ws, size_t ws_size,
                              hipStream_t stream) {
  const float* x      = (const float*)d_in[0];
  const float* c1w    = (const float*)d_in[1];
  const float* c1b    = (const float*)d_in[2];
  const float* bn1s   = (const float*)d_in[3];
  const float* bn1b   = (const float*)d_in[4];
  const float* bn1m   = (const float*)d_in[5];
  const float* bn1v   = (const float*)d_in[6];
  const float* se1w1  = (const float*)d_in[7];
  const float* se1b1  = (const float*)d_in[8];
  const float* se1w2  = (const float*)d_in[9];
  const float* se1b2  = (const float*)d_in[10];
  const float* c2w    = (const float*)d_in[11];
  const float* c2b    = (const float*)d_in[12];
  const float* bn2s   = (const float*)d_in[13];
  const float* bn2b   = (const float*)d_in[14];
  const float* bn2m   = (const float*)d_in[15];
  const float* bn2v   = (const float*)d_in[16];
  const float* se2w1  = (const float*)d_in[17];
  const float* se2b1  = (const float*)d_in[18];
  const float* se2w2  = (const float*)d_in[19];
  const float* se2b2  = (const float*)d_in[20];
  const float* c3w    = (const float*)d_in[21];
  const float* c3b    = (const float*)d_in[22];
  const float* bn3s   = (const float*)d_in[23];
  const float* bn3b   = (const float*)d_in[24];
  const float* bn3m   = (const float*)d_in[25];
  const float* bn3v   = (const float*)d_in[26];
  const float* efw    = (const float*)d_in[27];
  const float* efb    = (const float*)d_in[28];
  const float* ew     = (const float*)d_in[29];
  const float* e2nw   = (const float*)d_in[30];
  const float* e2nb   = (const float*)d_in[31];
  const float* a1w    = (const float*)d_in[32];
  const float* a1b    = (const float*)d_in[33];
  const float* a2w    = (const float*)d_in[34];
  const float* clsw   = (const float*)d_in[35];
  const float* clsb   = (const float*)d_in[36];
  const float* regw   = (const float*)d_in[37];
  const float* regb   = (const float*)d_in[38];

  float* ws = (float*)d_ws;
  float* h1     = ws;                        // 288*16*16*512 = 37,748,736 f
  float* h2     = h1 + 37748736;             // 288*32*8*128  =  9,437,184 f
  float* sesum1 = h2 + 9437184;              // 4608 f
  float* s1     = sesum1 + 4608;             // 4608 f
  float* sesum2 = s1 + 4608;                 // 9216 f
  float* s2     = sesum2 + 9216;             // 9216 f
  float* h3     = s2 + 9216;                 // 18432 f
  float* wf1    = h3 + 18432;                // 576 f
  float* wf2    = wf1 + 576;                 // 288*4608 = 1,327,104 f (~5.3 MB)

  k_fold1<<<18, 256, 0, stream>>>(c1w, bn1s, bn1v, wf1, sesum1);
  k_conv1<<<288 * 8, 256, 0, stream>>>(x, wf1, c1b, bn1s, bn1b, bn1m, bn1v, h1, sesum1);
  k_se<<<5, 64, 0, stream>>>(sesum1, 16, 4, 1.f / 8192.f, se1w1, se1b1, se1w2, se1b2, s1);
  k_fold2<<<288, 256, 0, stream>>>(c2w, bn2s, bn2v, s1, wf2, sesum2);
  k_conv2<<<288 * 8, 256, 0, stream>>>(h1, wf2, c2b, bn2s, bn2b, bn2m, bn2v, h2, sesum2);
  k_se<<<5, 64, 0, stream>>>(sesum2, 32, 8, 1.f / 1024.f, se2w1, se2b1, se2w2, se2b2, s2);
  k_conv3<<<288 * 4, 256, 0, stream>>>(h2, c3w, c3b, bn3s, bn3b, bn3m, bn3v, s2, h3);
  k_head<<<8, 256, 0, stream>>>(h3, efw, efb, ew, e2nw, e2nb, a1w, a1b, a2w,
                                clsw, clsb, regw, regb, (float*)d_out);
}